// Round 6
// baseline (76.384 us; speedup 1.0000x reference)
//
#include <hip/hip_runtime.h>

#define BATCH   16
#define CLEN    2048
#define DHEAD   2048
#define NT      256
#define ROWS    8                // rows per block (2 per wave)
#define NTILE   (CLEN / ROWS)    // 256 ctiles

typedef float f32x4 __attribute__((ext_vector_type(4)));

// ws layout (floats):
// [0..5]    : M00,M01,M10,M11,b2_0,b2_1
// [6..37]   : per-batch absmax mx[16][2]
// [40 ..]   : u0[2048], u1[2048], w[2048]
// [WS_PART] : prep partials [64 chunks][3][2048]
#define WS_MX   6
#define WS_U0   40
#define WS_U1   (40 + DHEAD)
#define WS_W    (40 + 2*DHEAD)
#define WS_PART (40 + 3*DHEAD)

// ---- prep A (17 blocks): block 0: M = Wq Wk^T, b2 = Wk @ bq; blocks 1..16: absmax of x[b] ----
__global__ void prep_small(const float* __restrict__ Wq, const float* __restrict__ Wk,
                           const float* __restrict__ bq, const float* __restrict__ x,
                           float* __restrict__ ws) {
    const int t = threadIdx.x;
    if (blockIdx.x == 0) {
        __shared__ float red[NT][6];
        float m00=0.f,m01=0.f,m10=0.f,m11=0.f,b20=0.f,b21=0.f;
        for (int d = t; d < DHEAD; d += NT) {
            float q0 = Wq[d], q1 = Wq[DHEAD + d];
            float k0 = Wk[d], k1 = Wk[DHEAD + d];
            float bb = bq[d];
            m00 += q0*k0; m01 += q0*k1; m10 += q1*k0; m11 += q1*k1;
            b20 += k0*bb; b21 += k1*bb;
        }
        red[t][0]=m00; red[t][1]=m01; red[t][2]=m10;
        red[t][3]=m11; red[t][4]=b20; red[t][5]=b21;
        __syncthreads();
        for (int s = NT/2; s > 0; s >>= 1) {
            if (t < s) {
                #pragma unroll
                for (int j = 0; j < 6; ++j) red[t][j] += red[t+s][j];
            }
            __syncthreads();
        }
        if (t < 6) ws[t] = red[0][t];
    } else {
        const int b = blockIdx.x - 1;
        __shared__ float red0[NT], red1[NT];
        const float* xb = x + (size_t)b * CLEN * 2;
        float m0 = 0.f, m1 = 0.f;
        for (int e = t; e < CLEN; e += NT) {
            float2 xe = *reinterpret_cast<const float2*>(xb + 2*e);
            m0 = fmaxf(m0, fabsf(xe.x));
            m1 = fmaxf(m1, fabsf(xe.y));
        }
        red0[t] = m0; red1[t] = m1;
        __syncthreads();
        for (int s = NT/2; s > 0; s >>= 1) {
            if (t < s) {
                red0[t] = fmaxf(red0[t], red0[t+s]);
                red1[t] = fmaxf(red1[t], red1[t+s]);
            }
            __syncthreads();
        }
        if (t == 0) { ws[WS_MX + 2*b] = red0[0]; ws[WS_MX + 2*b + 1] = red1[0]; }
    }
}

// ---------------- prep B1: partial u0,u1,w over 64 h-chunks of 32 ----------------
__global__ void prep_u_partial(const float* __restrict__ Wv, const float* __restrict__ bv,
                               const float* __restrict__ Wo, float* __restrict__ ws) {
    int o  = blockIdx.x * NT + threadIdx.x;      // column of Wo, 0..2047
    int hb = blockIdx.y * 32;                    // 64 chunks of 32 rows
    float p0=0.f, p1=0.f, pw=0.f;
    #pragma unroll 4
    for (int h = hb; h < hb + 32; ++h) {
        float wo = Wo[(size_t)h * DHEAD + o];
        p0 += Wv[h]         * wo;
        p1 += Wv[DHEAD + h] * wo;
        pw += bv[h]         * wo;
    }
    float* part = ws + WS_PART;
    part[((size_t)blockIdx.y*3 + 0)*DHEAD + o] = p0;
    part[((size_t)blockIdx.y*3 + 1)*DHEAD + o] = p1;
    part[((size_t)blockIdx.y*3 + 2)*DHEAD + o] = pw;
}

// ---------------- prep B2: reduce partials, add bo ----------------
__global__ void prep_u_final(const float* __restrict__ bo, float* __restrict__ ws) {
    int o = blockIdx.x * NT + threadIdx.x;
    const float* part = ws + WS_PART;
    float u0=0.f, u1=0.f, w=0.f;
    #pragma unroll
    for (int y = 0; y < 64; ++y) {
        u0 += part[((size_t)y*3 + 0)*DHEAD + o];
        u1 += part[((size_t)y*3 + 1)*DHEAD + o];
        w  += part[((size_t)y*3 + 2)*DHEAD + o];
    }
    ws[WS_U0 + o] = u0;
    ws[WS_U1 + o] = u1;
    ws[WS_W  + o] = w + bo[o];
}

__device__ __forceinline__ float waveSum(float v) {
    #pragma unroll
    for (int off = 32; off > 0; off >>= 1) v += __shfl_xor(v, off);
    return v;
}

// ---------------- fused: ONE-PASS per-wave softmax coeffs + burst store ----------------
// Shift by analytic upper bound m_ub = |g0|*mx0 + |g1|*mx1 >= true row max
// (softmax is shift-invariant; exp arg stays in [-~40, 0] -> no over/underflow).
// Flattened 1D grid decodes longest rows FIRST across all batches.
__launch_bounds__(NT, 4)
__global__ void attn_fused(const float* __restrict__ x, const float* __restrict__ ws,
                           float* __restrict__ out) {
    const int t    = threadIdx.x;
    const int lane = t & 63;
    const int wave = t >> 6;
    const int k    = blockIdx.x;
    const int b    = k & (BATCH - 1);
    const int base = (NTILE - 1 - (k >> 4)) * ROWS;   // longest rows dispatched first

    // issue u-register loads first; latency hides under the compute phase
    const f32x4 u0a = *reinterpret_cast<const f32x4*>(ws + WS_U0 + 4*t);
    const f32x4 u0b = *reinterpret_cast<const f32x4*>(ws + WS_U0 + 4*t + 1024);
    const f32x4 u1a = *reinterpret_cast<const f32x4*>(ws + WS_U1 + 4*t);
    const f32x4 u1b = *reinterpret_cast<const f32x4*>(ws + WS_U1 + 4*t + 1024);
    const f32x4 wva = *reinterpret_cast<const f32x4*>(ws + WS_W  + 4*t);
    const f32x4 wvb = *reinterpret_cast<const f32x4*>(ws + WS_W  + 4*t + 1024);

    __shared__ float sS[ROWS][2];

    const float M00 = ws[0], M01 = ws[1], M10 = ws[2], M11 = ws[3];
    const float B20 = ws[4], B21 = ws[5];
    const float mx0 = ws[WS_MX + 2*b], mx1 = ws[WS_MX + 2*b + 1];
    const float* xb = x + (size_t)b * CLEN * 2;

    // this wave's two rows
    const int ca = base + 2*wave;
    const int cb = ca + 1;
    const int na = ca + 1;          // row a causal length
    const int nb = cb + 1;          // = na + 1
    const float xa0 = xb[2*ca], xa1 = xb[2*ca + 1];
    const float xb0 = xb[2*cb], xb1 = xb[2*cb + 1];
    const float ga0 = M00*xa0 + M10*xa1 + B20;
    const float ga1 = M01*xa0 + M11*xa1 + B21;
    const float gb0 = M00*xb0 + M10*xb1 + B20;
    const float gb1 = M01*xb0 + M11*xb1 + B21;
    const float mua = fabsf(ga0)*mx0 + fabsf(ga1)*mx1;   // >= row-a max logit
    const float mub = fabsf(gb0)*mx0 + fabsf(gb1)*mx1;   // >= row-b max logit

    // single pass: exp + weighted sums, both rows per x load
    float psa=0.f, pa0=0.f, pa1=0.f, psb=0.f, pb0=0.f, pb1=0.f;
    for (int e = lane; e < nb; e += 64) {
        float2 xe = *reinterpret_cast<const float2*>(xb + 2*e);
        float la = ga0*xe.x + ga1*xe.y;
        float lb = gb0*xe.x + gb1*xe.y;
        float ea = (e < na) ? __expf(la - mua) : 0.f;
        float eb = __expf(lb - mub);
        psa += ea; pa0 += ea*xe.x; pa1 += ea*xe.y;
        psb += eb; pb0 += eb*xe.x; pb1 += eb*xe.y;
    }
    psa = waveSum(psa); pa0 = waveSum(pa0); pa1 = waveSum(pa1);
    psb = waveSum(psb); pb0 = waveSum(pb0); pb1 = waveSum(pb1);

    if (lane == 0) {
        float ia = 1.0f / psa, ib = 1.0f / psb;
        sS[2*wave][0]     = pa0 * ia;
        sS[2*wave][1]     = pa1 * ia;
        sS[2*wave + 1][0] = pb0 * ib;
        sS[2*wave + 1][1] = pb1 * ib;
    }
    __syncthreads();                      // the ONLY block barrier

    // store burst: 8 rows x 2 dwordx4 per thread, no barriers, normal stores
    float* oblk = out + ((size_t)(b * CLEN + base)) * DHEAD;
    #pragma unroll
    for (int r = 0; r < ROWS; ++r) {
        const float S0 = sS[r][0], S1 = sS[r][1];
        float* orow = oblk + (size_t)r * DHEAD;
        f32x4 ra, rb;
        ra.x = S0*u0a.x + S1*u1a.x + wva.x;
        ra.y = S0*u0a.y + S1*u1a.y + wva.y;
        ra.z = S0*u0a.z + S1*u1a.z + wva.z;
        ra.w = S0*u0a.w + S1*u1a.w + wva.w;
        rb.x = S0*u0b.x + S1*u1b.x + wvb.x;
        rb.y = S0*u0b.y + S1*u1b.y + wvb.y;
        rb.z = S0*u0b.z + S1*u1b.z + wvb.z;
        rb.w = S0*u0b.w + S1*u1b.w + wvb.w;
        *reinterpret_cast<f32x4*>(orow + 4*t)        = ra;
        *reinterpret_cast<f32x4*>(orow + 4*t + 1024) = rb;
    }
}

extern "C" void kernel_launch(void* const* d_in, const int* in_sizes, int n_in,
                              void* d_out, int out_size, void* d_ws, size_t ws_size,
                              hipStream_t stream) {
    const float* x  = (const float*)d_in[0];
    const float* Wk = (const float*)d_in[1];
    const float* bk = (const float*)d_in[2];  (void)bk; // cancels in softmax
    const float* Wq = (const float*)d_in[3];
    const float* bq = (const float*)d_in[4];
    const float* Wv = (const float*)d_in[5];
    const float* bv = (const float*)d_in[6];
    const float* Wo = (const float*)d_in[7];
    const float* bo = (const float*)d_in[8];
    float* out = (float*)d_out;
    float* ws  = (float*)d_ws;

    prep_small<<<1 + BATCH, NT, 0, stream>>>(Wq, Wk, bq, x, ws);
    prep_u_partial<<<dim3(DHEAD / NT, 64), NT, 0, stream>>>(Wv, bv, Wo, ws);
    prep_u_final<<<DHEAD / NT, NT, 0, stream>>>(bo, ws);
    attn_fused<<<NTILE * BATCH, NT, 0, stream>>>(x, ws, out);
}

// Round 7
// 67.691 us; speedup vs baseline: 1.1284x; 1.1284x over previous
//
#include <hip/hip_runtime.h>

#define BATCH   16
#define CLEN    2048
#define DHEAD   2048
#define NT      256
#define ROWS    8                 // rows per work item (2 per wave)
#define NTILE   (CLEN / ROWS)     // 256 ctiles
#define NWORK   (NTILE * BATCH)   // 4096 work items
#define GRID    1024              // persistent blocks (4 per CU)
#define KPB     (NWORK / GRID)    // 4 work items per block

typedef float f32x4 __attribute__((ext_vector_type(4)));

// ws layout (floats):
// [0..5]    : M00,M01,M10,M11,b2_0,b2_1
// [6..37]   : per-batch absmax mx[16][2]
// [40 ..]   : u0[2048], u1[2048], w[2048]
// [WS_PART] : prep partials [64 chunks][3][2048]
#define WS_MX   6
#define WS_U0   40
#define WS_U1   (40 + DHEAD)
#define WS_W    (40 + 2*DHEAD)
#define WS_PART (40 + 3*DHEAD)

// ---- prep B1 (+A fused): y<64: partial u chunks; y==64: M/b2 (x==0) or absmax (x>=1) ----
__global__ void prep_u_partial(const float* __restrict__ Wv, const float* __restrict__ bv,
                               const float* __restrict__ Wo, const float* __restrict__ Wq,
                               const float* __restrict__ Wk, const float* __restrict__ bq,
                               const float* __restrict__ x, float* __restrict__ ws) {
    const int t = threadIdx.x;
    if (blockIdx.y < 64) {
        int o  = blockIdx.x * NT + t;                // column of Wo, 0..2047
        int hb = blockIdx.y * 32;                    // 64 chunks of 32 rows
        float p0=0.f, p1=0.f, pw=0.f;
        #pragma unroll 4
        for (int h = hb; h < hb + 32; ++h) {
            float wo = Wo[(size_t)h * DHEAD + o];
            p0 += Wv[h]         * wo;
            p1 += Wv[DHEAD + h] * wo;
            pw += bv[h]         * wo;
        }
        float* part = ws + WS_PART;
        part[((size_t)blockIdx.y*3 + 0)*DHEAD + o] = p0;
        part[((size_t)blockIdx.y*3 + 1)*DHEAD + o] = p1;
        part[((size_t)blockIdx.y*3 + 2)*DHEAD + o] = pw;
    } else if (blockIdx.x == 0) {
        // M = Wq Wk^T (2x2), b2 = Wk @ bq
        __shared__ float red[NT][6];
        float m00=0.f,m01=0.f,m10=0.f,m11=0.f,b20=0.f,b21=0.f;
        for (int d = t; d < DHEAD; d += NT) {
            float q0 = Wq[d], q1 = Wq[DHEAD + d];
            float k0 = Wk[d], k1 = Wk[DHEAD + d];
            float bb = bq[d];
            m00 += q0*k0; m01 += q0*k1; m10 += q1*k0; m11 += q1*k1;
            b20 += k0*bb; b21 += k1*bb;
        }
        red[t][0]=m00; red[t][1]=m01; red[t][2]=m10;
        red[t][3]=m11; red[t][4]=b20; red[t][5]=b21;
        __syncthreads();
        for (int s = NT/2; s > 0; s >>= 1) {
            if (t < s) {
                #pragma unroll
                for (int j = 0; j < 6; ++j) red[t][j] += red[t+s][j];
            }
            __syncthreads();
        }
        if (t < 6) ws[t] = red[0][t];
    } else {
        // absmax of x[b] for b = 2*(x-1), 2*(x-1)+1   (x = 1..8)
        __shared__ float red0[NT], red1[NT];
        #pragma unroll
        for (int j = 0; j < 2; ++j) {
            const int b = 2 * (blockIdx.x - 1) + j;
            const float* xb = x + (size_t)b * CLEN * 2;
            float m0 = 0.f, m1 = 0.f;
            for (int e = t; e < CLEN; e += NT) {
                float2 xe = *reinterpret_cast<const float2*>(xb + 2*e);
                m0 = fmaxf(m0, fabsf(xe.x));
                m1 = fmaxf(m1, fabsf(xe.y));
            }
            red0[t] = m0; red1[t] = m1;
            __syncthreads();
            for (int s = NT/2; s > 0; s >>= 1) {
                if (t < s) {
                    red0[t] = fmaxf(red0[t], red0[t+s]);
                    red1[t] = fmaxf(red1[t], red1[t+s]);
                }
                __syncthreads();
            }
            if (t == 0) { ws[WS_MX + 2*b] = red0[0]; ws[WS_MX + 2*b + 1] = red1[0]; }
            __syncthreads();
        }
    }
}

// ---------------- prep B2: reduce partials, add bo ----------------
__global__ void prep_u_final(const float* __restrict__ bo, float* __restrict__ ws) {
    int o = blockIdx.x * NT + threadIdx.x;
    const float* part = ws + WS_PART;
    float u0=0.f, u1=0.f, w=0.f;
    #pragma unroll
    for (int y = 0; y < 64; ++y) {
        u0 += part[((size_t)y*3 + 0)*DHEAD + o];
        u1 += part[((size_t)y*3 + 1)*DHEAD + o];
        w  += part[((size_t)y*3 + 2)*DHEAD + o];
    }
    ws[WS_U0 + o] = u0;
    ws[WS_U1 + o] = u1;
    ws[WS_W  + o] = w + bo[o];
}

__device__ __forceinline__ float waveSum(float v) {
    #pragma unroll
    for (int off = 32; off > 0; off >>= 1) v += __shfl_xor(v, off);
    return v;
}

// ---------------- persistent fused kernel ----------------
// 1024 blocks x 4 work items. Stores from item i drain while item i+1
// computes (no dependent wait) -> continuous fill-like write stream.
// One-pass softmax via analytic upper bound (shift-invariant, exact).
__launch_bounds__(NT, 4)
__global__ void attn_fused(const float* __restrict__ x, const float* __restrict__ ws,
                           float* __restrict__ out) {
    const int t    = threadIdx.x;
    const int lane = t & 63;
    const int wave = t >> 6;

    // u fragments in registers, loaded ONCE per block (amortized over KPB items)
    const f32x4 u0a = *reinterpret_cast<const f32x4*>(ws + WS_U0 + 4*t);
    const f32x4 u0b = *reinterpret_cast<const f32x4*>(ws + WS_U0 + 4*t + 1024);
    const f32x4 u1a = *reinterpret_cast<const f32x4*>(ws + WS_U1 + 4*t);
    const f32x4 u1b = *reinterpret_cast<const f32x4*>(ws + WS_U1 + 4*t + 1024);
    const f32x4 wva = *reinterpret_cast<const f32x4*>(ws + WS_W  + 4*t);
    const f32x4 wvb = *reinterpret_cast<const f32x4*>(ws + WS_W  + 4*t + 1024);

    const float M00 = ws[0], M01 = ws[1], M10 = ws[2], M11 = ws[3];
    const float B20 = ws[4], B21 = ws[5];

    __shared__ float sS[ROWS][2];

    for (int it = 0; it < KPB; ++it) {
        const int k    = blockIdx.x + it * GRID;
        const int b    = k & (BATCH - 1);
        const int base = (k >> 4) * ROWS;
        const float mx0 = ws[WS_MX + 2*b], mx1 = ws[WS_MX + 2*b + 1];
        const float* xb = x + (size_t)b * CLEN * 2;

        // this wave's two rows
        const int ca = base + 2*wave;
        const int cb = ca + 1;
        const int na = ca + 1;          // row a causal length
        const int nb = cb + 1;          // = na + 1
        const float xa0 = xb[2*ca], xa1 = xb[2*ca + 1];
        const float xb0 = xb[2*cb], xb1 = xb[2*cb + 1];
        const float ga0 = M00*xa0 + M10*xa1 + B20;
        const float ga1 = M01*xa0 + M11*xa1 + B21;
        const float gb0 = M00*xb0 + M10*xb1 + B20;
        const float gb1 = M01*xb0 + M11*xb1 + B21;
        const float mua = fabsf(ga0)*mx0 + fabsf(ga1)*mx1;   // >= row-a max logit
        const float mub = fabsf(gb0)*mx0 + fabsf(gb1)*mx1;   // >= row-b max logit

        // single pass: exp + weighted sums, both rows per x load
        float psa=0.f, pa0=0.f, pa1=0.f, psb=0.f, pb0=0.f, pb1=0.f;
        for (int e = lane; e < nb; e += 64) {
            float2 xe = *reinterpret_cast<const float2*>(xb + 2*e);
            float la = ga0*xe.x + ga1*xe.y;
            float lb = gb0*xe.x + gb1*xe.y;
            float ea = (e < na) ? __expf(la - mua) : 0.f;
            float eb = __expf(lb - mub);
            psa += ea; pa0 += ea*xe.x; pa1 += ea*xe.y;
            psb += eb; pb0 += eb*xe.x; pb1 += eb*xe.y;
        }
        psa = waveSum(psa); pa0 = waveSum(pa0); pa1 = waveSum(pa1);
        psb = waveSum(psb); pb0 = waveSum(pb0); pb1 = waveSum(pb1);

        if (lane == 0) {
            float ia = 1.0f / psa, ib = 1.0f / psb;
            sS[2*wave][0]     = pa0 * ia;
            sS[2*wave][1]     = pa1 * ia;
            sS[2*wave + 1][0] = pb0 * ib;
            sS[2*wave + 1][1] = pb1 * ib;
        }
        __syncthreads();

        // store burst: 8 rows x 2 dwordx4 per thread; stores keep draining
        // through the next iteration's compute phase (no dependent wait).
        float* oblk = out + ((size_t)(b * CLEN + base)) * DHEAD;
        #pragma unroll
        for (int r = 0; r < ROWS; ++r) {
            const float S0 = sS[r][0], S1 = sS[r][1];
            float* orow = oblk + (size_t)r * DHEAD;
            f32x4 ra, rb;
            ra.x = S0*u0a.x + S1*u1a.x + wva.x;
            ra.y = S0*u0a.y + S1*u1a.y + wva.y;
            ra.z = S0*u0a.z + S1*u1a.z + wva.z;
            ra.w = S0*u0a.w + S1*u1a.w + wva.w;
            rb.x = S0*u0b.x + S1*u1b.x + wvb.x;
            rb.y = S0*u0b.y + S1*u1b.y + wvb.y;
            rb.z = S0*u0b.z + S1*u1b.z + wvb.z;
            rb.w = S0*u0b.w + S1*u1b.w + wvb.w;
            *reinterpret_cast<f32x4*>(orow + 4*t)        = ra;
            *reinterpret_cast<f32x4*>(orow + 4*t + 1024) = rb;
        }
        __syncthreads();   // protect sS for next iteration's writers
    }
}

extern "C" void kernel_launch(void* const* d_in, const int* in_sizes, int n_in,
                              void* d_out, int out_size, void* d_ws, size_t ws_size,
                              hipStream_t stream) {
    const float* x  = (const float*)d_in[0];
    const float* Wk = (const float*)d_in[1];
    const float* bk = (const float*)d_in[2];  (void)bk; // cancels in softmax
    const float* Wq = (const float*)d_in[3];
    const float* bq = (const float*)d_in[4];
    const float* Wv = (const float*)d_in[5];
    const float* bv = (const float*)d_in[6];
    const float* Wo = (const float*)d_in[7];
    const float* bo = (const float*)d_in[8];
    float* out = (float*)d_out;
    float* ws  = (float*)d_ws;

    prep_u_partial<<<dim3(DHEAD / NT, 65), NT, 0, stream>>>(Wv, bv, Wo, Wq, Wk, bq, x, ws);
    prep_u_final<<<DHEAD / NT, NT, 0, stream>>>(bo, ws);
    attn_fused<<<GRID, NT, 0, stream>>>(x, ws, out);
}